// Round 9
// baseline (254.872 us; speedup 1.0000x reference)
//
#include <hip/hip_runtime.h>
#include <math.h>

namespace {

constexpr int Bn = 64, Cn = 128, Tn = 512, Hn = 256;
constexpr int MR = 128;        // t-rows per block (4 waves x 32)
constexpr int TB = Tn / MR;    // 4 -> grid 256 (1 block/CU)
constexpr float LN_EPS = 1e-5f;

// Packed weight geometry (in shorts). Fragment-linear layout per chunk:
// frag(granule g, col n) at ((g*N + n)*8); granule g = (k_in_chunk)>>3.
constexpr int C1 = 16384;      // shorts per L1 chunk (64k x 256n = 32 KB)
constexpr int C2 = 8192;       // shorts per L2 chunk (64k x 128n = 16 KB)
constexpr int W2S = 18 * C1;   // short offset of L2 chunk region
constexpr int SST = 266;       // stash row stride in shorts (133 dwords: 5r mod 32 banks)

typedef __attribute__((ext_vector_type(8))) short short8;
typedef __attribute__((ext_vector_type(16))) float f32x16;

__device__ __forceinline__ unsigned short f2bf(float f) {
  unsigned int u = __builtin_bit_cast(unsigned int, f);
  u = (u + 0x7fffu + ((u >> 16) & 1u)) >> 16;
  return (unsigned short)u;
}
__device__ __forceinline__ float bf2f(unsigned short u) {
  unsigned int v = (unsigned int)u << 16;
  return __builtin_bit_cast(float, v);
}
__device__ __forceinline__ float siluf(float z) {
  return z * __builtin_amdgcn_rcpf(1.0f + __expf(-z));
}

// Closed-form uniform cubic B-spline on grid g[j]=0.4*(j-3)-1; returns the
// 8 basis values (j=0..7) packed bf16. Matches the reference recursion
// (half-open cells, all-zero outside [-2.2, 2.2)).
__device__ __forceinline__ short8 spline_pack(float z) {
  const float p = z * 2.5f + 5.5f;
  const float fi = floorf(p);
  const int ib = (int)fi - 3;  // first nonzero j
  const float u = p - fi;
  const float u2 = u * u, u3 = u2 * u, tt = 1.0f - u;
  const float w0 = tt * tt * tt * (1.0f / 6.0f);
  const float w1 = (3.0f * u3 - 6.0f * u2 + 4.0f) * (1.0f / 6.0f);
  const float w2 = (-3.0f * u3 + 3.0f * u2 + 3.0f * u + 1.0f) * (1.0f / 6.0f);
  const float w3 = u3 * (1.0f / 6.0f);
  short8 r;
#pragma unroll
  for (int j = 0; j < 8; ++j) {
    const int d = j - ib;
    const float v =
        (d == 0) ? w0 : (d == 1) ? w1 : (d == 2) ? w2 : (d == 3) ? w3 : 0.0f;
    r[j] = (short)f2bf(v);
  }
  return r;
}

}  // namespace

// ---------------------------------------------------------------------------
// Prep: pack weights fragment-linear; per-batch LN partial sums; bf16
// transpose of ln_w/ln_b to [c][t].
// L1 chunks 0..15 spline (k=c*8+j), 16..17 silu (k=1024+c).
// L2 chunks 18..49 spline (k=h*8+j), 50..53 silu (k=2048+h).
// ---------------------------------------------------------------------------
__global__ __launch_bounds__(256) void kan_prep(
    const float* __restrict__ U, const float* __restrict__ ln_w,
    const float* __restrict__ ln_b, const float* __restrict__ bw1,
    const float* __restrict__ sw1, const float* __restrict__ ss1,
    const float* __restrict__ bw2, const float* __restrict__ sw2,
    const float* __restrict__ ss2, unsigned short* __restrict__ Wp,
    unsigned short* __restrict__ lnwT, unsigned short* __restrict__ lnbT,
    float* __restrict__ stats) {
  __shared__ float red[2][4];
  const int blk = blockIdx.x;
  if (blk < 128) {  // ---- W1: idx = h*128 + c ----
    const int idx = blk * 256 + threadIdx.x;
    const int h = idx >> 7, c = idx & 127;
    const float sc = ss1[idx];
    const float* spw = sw1 + (size_t)idx * 8;
    short8 v;
#pragma unroll
    for (int j = 0; j < 8; ++j) v[j] = (short)f2bf(spw[j] * sc);
    *(short8*)(Wp + (size_t)(c >> 3) * C1 + ((c & 7) * 256 + h) * 8) = v;
    Wp[(size_t)(16 + (c >> 6)) * C1 + (((c >> 3) & 7) * 256 + h) * 8 +
       (c & 7)] = f2bf(bw1[idx]);
  } else if (blk < 256) {  // ---- W2: idx = c*256 + h ----
    const int idx = (blk - 128) * 256 + threadIdx.x;
    const int c = idx >> 8, h = idx & 255;
    const float sc = ss2[idx];
    const float* spw = sw2 + (size_t)idx * 8;
    short8 v;
#pragma unroll
    for (int j = 0; j < 8; ++j) v[j] = (short)f2bf(spw[j] * sc);
    *(short8*)(Wp + W2S + (size_t)(h >> 3) * C2 + ((h & 7) * 128 + c) * 8) = v;
    Wp[W2S + (size_t)(32 + (h >> 6)) * C2 + (((h >> 3) & 7) * 128 + c) * 8 +
       (h & 7)] = f2bf(bw2[idx]);
  } else if (blk < 512) {  // ---- LN stats partials ----
    const int sblk = blk - 256;
    const int b = sblk >> 2, q = sblk & 3;
    const float4* p =
        (const float4*)(U + (size_t)b * (Cn * Tn) + q * (Cn * Tn / 4));
    float s = 0.f, s2 = 0.f;
#pragma unroll 4
    for (int i = threadIdx.x; i < (Cn * Tn / 4) / 4; i += 256) {
      const float4 v4 = p[i];
      s += v4.x + v4.y + v4.z + v4.w;
      s2 += v4.x * v4.x + v4.y * v4.y + v4.z * v4.z + v4.w * v4.w;
    }
#pragma unroll
    for (int off = 32; off > 0; off >>= 1) {
      s += __shfl_down(s, off);
      s2 += __shfl_down(s2, off);
    }
    if ((threadIdx.x & 63) == 0) {
      red[0][threadIdx.x >> 6] = s;
      red[1][threadIdx.x >> 6] = s2;
    }
    __syncthreads();
    if (threadIdx.x == 0) {
      stats[b * 8 + q * 2 + 0] = red[0][0] + red[0][1] + red[0][2] + red[0][3];
      stats[b * 8 + q * 2 + 1] = red[1][0] + red[1][1] + red[1][2] + red[1][3];
    }
  } else {  // ---- ln_w/ln_b transpose to bf16 [c][t] ----
    const int bb = blk - 512;  // 0..127
    const float* src = (bb < 64) ? ln_w : ln_b;
    unsigned short* dst = (bb < 64) ? lnwT : lnbT;
    const int base = (bb & 63) * 1024;
#pragma unroll
    for (int e2 = 0; e2 < 4; ++e2) {
      const int i = base + (int)threadIdx.x + e2 * 256;  // c*512 + t
      dst[i] = f2bf(src[(i & 511) * Cn + (i >> 9)]);
    }
  }
}

// ---------------------------------------------------------------------------
// Fused LN -> KAN1 -> KAN2 -> residual. 256 blocks x 256 threads (4 waves).
// A-fragments computed IN REGISTERS (spline_pack of lane's own z) — no A-LDS.
// Each wave owns 32 t-rows and full N; weights DMA'd to LDS (double-buffered,
// fragment-linear, conflict-free). h1 kept wave-private in an LDS stash.
// One barrier per 64-k chunk (B-dbuf only).
// ---------------------------------------------------------------------------
__global__ __launch_bounds__(256, 1) void kan_fused(
    const float* __restrict__ U, const unsigned short* __restrict__ lnwT,
    const unsigned short* __restrict__ lnbT,
    const unsigned short* __restrict__ Wp, const float* __restrict__ stats,
    float* __restrict__ out) {
  __shared__ __align__(16) unsigned short s_b[2][C1];   // 65,536 B
  __shared__ __align__(16) unsigned short s_stash[4][32 * SST];  // 68,096 B

  const int tid = threadIdx.x;
  const int b = blockIdx.x >> 2;
  const int t0 = (blockIdx.x & 3) * MR;

  const float* sp = stats + b * 8;
  const float ssum = sp[0] + sp[2] + sp[4] + sp[6];
  const float ssq = sp[1] + sp[3] + sp[5] + sp[7];
  const float inv_n = 1.0f / (float)(Cn * Tn);
  const float mean = ssum * inv_n;
  const float rstd = rsqrtf(ssq * inv_n - mean * mean + LN_EPS);

  const int w = tid >> 6, l = tid & 63;
  const int ln31 = l & 31, hl = l >> 5;
  const int trow = t0 + w * 32 + ln31;  // this lane's t-row
  unsigned short* stash = s_stash[w];

  auto stage = [&](int q, int buf) {
    const char* src =
        (const char*)Wp + ((q < 18) ? (size_t)q * 32768
                                    : (size_t)589824 + (size_t)(q - 18) * 16384);
    char* dst = (char*)&s_b[buf][0];
    const int n = (q < 18) ? 32 : 16;
    for (int i = w; i < n; i += 4) {
      __builtin_amdgcn_global_load_lds(
          (const __attribute__((address_space(1))) unsigned int*)(src +
                                                                  i * 1024 +
                                                                  l * 16),
          (__attribute__((address_space(3))) unsigned int*)(dst + i * 1024),
          16, 0, 0);
    }
  };

  // ==================== Layer 1: 18 chunks of k=64 ====================
  f32x16 acc1[8] = {};
  stage(0, 0);
  __syncthreads();
  for (int q = 0; q < 18; ++q) {
    const int buf = q & 1;
    stage(q + 1, buf ^ 1);  // q=17 stages chunk 18 (first L2 chunk)
    const unsigned short* bb = &s_b[buf][0];
#pragma unroll
    for (int ks = 0; ks < 4; ++ks) {
      short8 a;
      if (q < 16) {  // spline chunk: lane's A-frag = spline of one z
        const int c = q * 8 + ks * 2 + hl;
        const float uv = U[((size_t)b * Cn + c) * Tn + trow];
        const float z = (uv - mean) * rstd * bf2f(lnwT[c * Tn + trow]) +
                        bf2f(lnbT[c * Tn + trow]);
        stash[ln31 * SST + c] = f2bf(z);  // keep z for silu chunks
        a = spline_pack(z);
      } else {  // silu chunk: 8 silus of stashed z
        const int cb = (q - 16) * 64 + ks * 16 + hl * 8;
        const short8 zs = *(const short8*)&stash[ln31 * SST + cb];
#pragma unroll
        for (int j = 0; j < 8; ++j)
          a[j] = (short)f2bf(siluf(bf2f((unsigned short)zs[j])));
      }
      const unsigned short* fb = bb + ((ks * 2 + hl) * 256 + ln31) * 8;
#pragma unroll
      for (int nt = 0; nt < 8; ++nt) {
        const short8 bfr = *(const short8*)(fb + nt * 256);
        acc1[nt] =
            __builtin_amdgcn_mfma_f32_32x32x16_bf16(a, bfr, acc1[nt], 0, 0, 0);
      }
    }
    __syncthreads();
  }

  // ---- h1 -> wave-private stash (overwrites z; wave-local, no barrier) ----
#pragma unroll
  for (int nt = 0; nt < 8; ++nt)
#pragma unroll
    for (int r = 0; r < 16; ++r) {
      const int row = 4 * hl + (r & 3) + 8 * (r >> 2);
      stash[row * SST + nt * 32 + ln31] = f2bf(acc1[nt][r]);
    }

  // ==================== Layer 2: 36 chunks of k=64 ====================
  f32x16 acc2[4] = {};
  for (int q = 18; q < 54; ++q) {
    const int buf = q & 1;
    if (q < 53) stage(q + 1, buf ^ 1);
    const unsigned short* bb = &s_b[buf][0];
#pragma unroll
    for (int ks = 0; ks < 4; ++ks) {
      short8 a;
      if (q < 50) {  // spline chunk over h
        const int h = (q - 18) * 8 + ks * 2 + hl;
        a = spline_pack(bf2f(stash[ln31 * SST + h]));
      } else {  // silu chunk over h
        const int hb = (q - 50) * 64 + ks * 16 + hl * 8;
        const short8 zs = *(const short8*)&stash[ln31 * SST + hb];
#pragma unroll
        for (int j = 0; j < 8; ++j)
          a[j] = (short)f2bf(siluf(bf2f((unsigned short)zs[j])));
      }
      const unsigned short* fb = bb + ((ks * 2 + hl) * 128 + ln31) * 8;
#pragma unroll
      for (int nt = 0; nt < 4; ++nt) {
        const short8 bfr = *(const short8*)(fb + nt * 256);
        acc2[nt] =
            __builtin_amdgcn_mfma_f32_32x32x16_bf16(a, bfr, acc2[nt], 0, 0, 0);
      }
    }
    __syncthreads();
  }

  // ==================== epilogue: LDS bounce -> coalesced residual ========
  // obuf[w][c][row ^ ((c&7)<<2)] (f32) reuses the B-buffer region (64 KB).
  float* ob = (float*)&s_b[0][0];
#pragma unroll
  for (int nt = 0; nt < 4; ++nt)
#pragma unroll
    for (int r = 0; r < 16; ++r) {
      const int c = nt * 32 + ln31;
      const int row = 4 * hl + (r & 3) + 8 * (r >> 2);
      ob[w * 4096 + c * 32 + (row ^ ((c & 7) << 2))] = acc2[nt][r];
    }
  __syncthreads();
  // Drain: 4096 float4 slots = 4 wave-regions x 128 c x 8 row-groups.
#pragma unroll 4
  for (int it = 0; it < 16; ++it) {
    const int slot = it * 256 + tid;
    const int ws = slot >> 10, rem = slot & 1023;
    const int c = rem >> 3, rg = rem & 7;
    const int p4 = (rg * 4) ^ ((c & 7) << 2);
    const float4 v = *(const float4*)&ob[ws * 4096 + c * 32 + p4];
    const size_t ga = ((size_t)b * Cn + c) * Tn + t0 + ws * 32 + rg * 4;
    const float4 u4 = *(const float4*)&U[ga];
    float4 o;
    o.x = u4.x + v.x;
    o.y = u4.y + v.y;
    o.z = u4.z + v.z;
    o.w = u4.w + v.w;
    *(float4*)&out[ga] = o;
  }
}

extern "C" void kernel_launch(void* const* d_in, const int* in_sizes, int n_in,
                              void* d_out, int out_size, void* d_ws,
                              size_t ws_size, hipStream_t stream) {
  const float* U = (const float*)d_in[0];
  const float* ln_w = (const float*)d_in[1];
  const float* ln_b = (const float*)d_in[2];
  const float* bw1 = (const float*)d_in[3];
  const float* sw1 = (const float*)d_in[4];
  const float* ss1 = (const float*)d_in[5];
  const float* bw2 = (const float*)d_in[6];
  const float* sw2 = (const float*)d_in[7];
  const float* ss2 = (const float*)d_in[8];
  float* out = (float*)d_out;

  char* ws = (char*)d_ws;
  float* stats = (float*)ws;                            // 4 KB
  unsigned short* lnwT = (unsigned short*)(ws + 4096);  // 128 KB
  unsigned short* lnbT = lnwT + Cn * Tn;                // 128 KB
  unsigned short* Wp = lnbT + Cn * Tn;                  // 1,179,648 B packed W

  kan_prep<<<640, 256, 0, stream>>>(U, ln_w, ln_b, bw1, sw1, ss1, bw2, sw2,
                                    ss2, Wp, lnwT, lnbT, stats);
  kan_fused<<<Bn * TB, 256, 0, stream>>>(U, lnwT, lnbT, Wp, stats, out);
}

// Round 10
// 252.234 us; speedup vs baseline: 1.0105x; 1.0105x over previous
//
#include <hip/hip_runtime.h>
#include <math.h>

namespace {

constexpr int Bn = 64, Cn = 128, Tn = 512, Hn = 256;
constexpr int MR = 64;         // t-rows per block (2 groups x 32)
constexpr int TB = Tn / MR;    // 8 -> grid 512 (2 blocks/CU)
constexpr float LN_EPS = 1e-5f;

// Weight chunking: k=32 per chunk (4 granules of 8).
// L1: chunks 0..31 spline (c = q*4+g), 32..35 silu (c = (q-32)*32+g*8+j). 16 KB each.
// L2: chunks 36..99 spline (h = (q-36)*4+g), 100..107 silu. 8 KB each.
constexpr int L2BASE = 294912;  // short offset of L2 region (36*8192)
constexpr int SST = 266;        // stash row stride in shorts
constexpr float4* kNull = nullptr;

typedef __attribute__((ext_vector_type(8))) short short8;
typedef __attribute__((ext_vector_type(16))) float f32x16;

__device__ __forceinline__ unsigned short f2bf(float f) {
  unsigned int u = __builtin_bit_cast(unsigned int, f);
  u = (u + 0x7fffu + ((u >> 16) & 1u)) >> 16;
  return (unsigned short)u;
}
__device__ __forceinline__ float bf2f(unsigned short u) {
  unsigned int v = (unsigned int)u << 16;
  return __builtin_bit_cast(float, v);
}
__device__ __forceinline__ float siluf(float z) {
  return z * __builtin_amdgcn_rcpf(1.0f + __expf(-z));
}

// Closed-form uniform cubic B-spline on grid g[j]=0.4*(j-3)-1; 8 bases bf16.
__device__ __forceinline__ short8 spline_pack(float z) {
  const float p = z * 2.5f + 5.5f;
  const float fi = floorf(p);
  const int ib = (int)fi - 3;
  const float u = p - fi;
  const float u2 = u * u, u3 = u2 * u, tt = 1.0f - u;
  const float w0 = tt * tt * tt * (1.0f / 6.0f);
  const float w1 = (3.0f * u3 - 6.0f * u2 + 4.0f) * (1.0f / 6.0f);
  const float w2 = (-3.0f * u3 + 3.0f * u2 + 3.0f * u + 1.0f) * (1.0f / 6.0f);
  const float w3 = u3 * (1.0f / 6.0f);
  short8 r;
#pragma unroll
  for (int j = 0; j < 8; ++j) {
    const int d = j - ib;
    const float v =
        (d == 0) ? w0 : (d == 1) ? w1 : (d == 2) ? w2 : (d == 3) ? w3 : 0.0f;
    r[j] = (short)f2bf(v);
  }
  return r;
}

__device__ __forceinline__ short8 silu8(short8 zs) {
  short8 a;
#pragma unroll
  for (int j = 0; j < 8; ++j)
    a[j] = (short)f2bf(siluf(bf2f((unsigned short)zs[j])));
  return a;
}

}  // namespace

// ---------------------------------------------------------------------------
// Prep: pack weights fragment-linear per k=32 chunk; per-batch LN partial
// sums; bf16 transpose of ln_w/ln_b to [c][t].
// ---------------------------------------------------------------------------
__global__ __launch_bounds__(256) void kan_prep(
    const float* __restrict__ U, const float* __restrict__ ln_w,
    const float* __restrict__ ln_b, const float* __restrict__ bw1,
    const float* __restrict__ sw1, const float* __restrict__ ss1,
    const float* __restrict__ bw2, const float* __restrict__ sw2,
    const float* __restrict__ ss2, unsigned short* __restrict__ Wp,
    unsigned short* __restrict__ lnwT, unsigned short* __restrict__ lnbT,
    float* __restrict__ stats) {
  __shared__ float red[2][4];
  const int blk = blockIdx.x;
  if (blk < 128) {  // ---- W1: idx = h*128 + c ----
    const int idx = blk * 256 + threadIdx.x;
    const int h = idx >> 7, c = idx & 127;
    const float sc = ss1[idx];
    const float* spw = sw1 + (size_t)idx * 8;
    short8 v;
#pragma unroll
    for (int j = 0; j < 8; ++j) v[j] = (short)f2bf(spw[j] * sc);
    *(short8*)(Wp + (size_t)(c >> 2) * 8192 + ((c & 3) * 256 + h) * 8) = v;
    Wp[(size_t)(32 + (c >> 5)) * 8192 + (((c >> 3) & 3) * 256 + h) * 8 +
       (c & 7)] = f2bf(bw1[idx]);
  } else if (blk < 256) {  // ---- W2: idx = c*256 + h ----
    const int idx = (blk - 128) * 256 + threadIdx.x;
    const int c = idx >> 8, h = idx & 255;
    const float sc = ss2[idx];
    const float* spw = sw2 + (size_t)idx * 8;
    short8 v;
#pragma unroll
    for (int j = 0; j < 8; ++j) v[j] = (short)f2bf(spw[j] * sc);
    *(short8*)(Wp + L2BASE + (size_t)(h >> 2) * 4096 + ((h & 3) * 128 + c) * 8) =
        v;
    Wp[L2BASE + (size_t)(64 + (h >> 5)) * 4096 + (((h >> 3) & 3) * 128 + c) * 8 +
       (h & 7)] = f2bf(bw2[idx]);
  } else if (blk < 512) {  // ---- LN stats partials ----
    const int sblk = blk - 256;
    const int b = sblk >> 2, q = sblk & 3;
    const float4* p =
        (const float4*)(U + (size_t)b * (Cn * Tn) + q * (Cn * Tn / 4));
    float s = 0.f, s2 = 0.f;
#pragma unroll 4
    for (int i = threadIdx.x; i < (Cn * Tn / 4) / 4; i += 256) {
      const float4 v4 = p[i];
      s += v4.x + v4.y + v4.z + v4.w;
      s2 += v4.x * v4.x + v4.y * v4.y + v4.z * v4.z + v4.w * v4.w;
    }
#pragma unroll
    for (int off = 32; off > 0; off >>= 1) {
      s += __shfl_down(s, off);
      s2 += __shfl_down(s2, off);
    }
    if ((threadIdx.x & 63) == 0) {
      red[0][threadIdx.x >> 6] = s;
      red[1][threadIdx.x >> 6] = s2;
    }
    __syncthreads();
    if (threadIdx.x == 0) {
      stats[b * 8 + q * 2 + 0] = red[0][0] + red[0][1] + red[0][2] + red[0][3];
      stats[b * 8 + q * 2 + 1] = red[1][0] + red[1][1] + red[1][2] + red[1][3];
    }
  } else {  // ---- ln_w/ln_b transpose to bf16 [c][t] ----
    const int bb = blk - 512;  // 0..127
    const float* src = (bb < 64) ? ln_w : ln_b;
    unsigned short* dst = (bb < 64) ? lnwT : lnbT;
    const int base = (bb & 63) * 1024;
#pragma unroll
    for (int e2 = 0; e2 < 4; ++e2) {
      const int i = base + (int)threadIdx.x + e2 * 256;  // c*512 + t
      dst[i] = f2bf(src[(i & 511) * Cn + (i >> 9)]);
    }
  }
}

// ---------------------------------------------------------------------------
// Fused LN -> KAN1 -> KAN2 -> residual. 512 blocks x 256 threads (4 waves),
// 66.8 KB LDS -> 2 blocks/CU (8 waves/CU, two barrier domains).
// A-fragments in registers; weights DMA'd (k=32 chunks, dbuf); wave split:
// 2 row-groups x 2 N-halves (act VALU duplicated x2 only).
// ---------------------------------------------------------------------------
__global__ __launch_bounds__(256, 2) void kan_fused(
    const float* __restrict__ U, const unsigned short* __restrict__ lnwT,
    const unsigned short* __restrict__ lnbT,
    const unsigned short* __restrict__ Wp, const float* __restrict__ stats,
    float* __restrict__ out) {
  __shared__ __align__(16) unsigned short s_b[2][8192];      // 32 KB dbuf
  __shared__ __align__(16) unsigned short s_stash[MR * SST];  // 34,048 B

  const int tid = threadIdx.x;
  const int b = blockIdx.x >> 3;
  const int t0 = (blockIdx.x & 7) * MR;

  const float* sp = stats + b * 8;
  const float ssum = sp[0] + sp[2] + sp[4] + sp[6];
  const float ssq = sp[1] + sp[3] + sp[5] + sp[7];
  const float inv_n = 1.0f / (float)(Cn * Tn);
  const float mean = ssum * inv_n;
  const float rstd = rsqrtf(ssq * inv_n - mean * mean + LN_EPS);

  const int w = tid >> 6, l = tid & 63;
  const int ln31 = l & 31, hl = l >> 5;
  const int gr = w & 1;   // row-group: rows gr*32..+31
  const int nh = w >> 1;  // N-half
  const int lrow = gr * 32 + ln31;
  const int trow = t0 + lrow;

  auto stage = [&](int q, int buf) {
    if (q >= 108) return;
    const char* src =
        (const char*)Wp +
        ((q < 36) ? (size_t)q * 16384 : (size_t)589824 + (size_t)(q - 36) * 8192);
    char* dst = (char*)&s_b[buf][0];
    const int nIt = (q < 36) ? 4 : 2;
    for (int i = 0; i < nIt; ++i) {
      __builtin_amdgcn_global_load_lds(
          (const __attribute__((address_space(1))) unsigned int*)(src + i * 4096 +
                                                                  tid * 16),
          (__attribute__((address_space(3))) unsigned int*)(dst + i * 4096 +
                                                            tid * 16),
          16, 0, 0);
    }
  };

  // ==================== Layer 1: chunks 0..35 (k=32 each) ====================
  f32x16 acc1[4] = {};
  stage(0, 0);
  __syncthreads();
  for (int q = 0; q < 36; ++q) {
    const int buf = q & 1;
    stage(q + 1, buf ^ 1);
    const unsigned short* bb = &s_b[buf][0];
#pragma unroll
    for (int ks = 0; ks < 2; ++ks) {
      const int g = ks * 2 + hl;  // granule 0..3
      short8 a;
      if (q < 32) {  // spline: lane's A-frag = spline of its own z
        const int c = q * 4 + g;
        const float uv = U[((size_t)b * Cn + c) * Tn + trow];
        const float z = (uv - mean) * rstd * bf2f(lnwT[c * Tn + trow]) +
                        bf2f(lnbT[c * Tn + trow]);
        if (nh == 0) s_stash[lrow * SST + c] = f2bf(z);
        a = spline_pack(z);
      } else {  // silu: 8 silus of stashed z
        const int cb = (q - 32) * 32 + g * 8;
        a = silu8(*(const short8*)&s_stash[lrow * SST + cb]);
      }
      const unsigned short* fb = bb + (g * 256 + nh * 128 + ln31) * 8;
#pragma unroll
      for (int f = 0; f < 4; ++f) {
        const short8 bfr = *(const short8*)(fb + f * 32 * 8);
        acc1[f] =
            __builtin_amdgcn_mfma_f32_32x32x16_bf16(a, bfr, acc1[f], 0, 0, 0);
      }
    }
    __syncthreads();
  }

  // ---- h1 -> stash (cols nh*128..+127 per wave; overwrites z region) ----
#pragma unroll
  for (int f = 0; f < 4; ++f)
#pragma unroll
    for (int r = 0; r < 16; ++r) {
      const int row = 4 * hl + (r & 3) + 8 * (r >> 2);
      s_stash[(gr * 32 + row) * SST + nh * 128 + f * 32 + ln31] =
          f2bf(acc1[f][r]);
    }
  __syncthreads();

  // ==================== Layer 2: chunks 36..107 ====================
  f32x16 acc2[2] = {};
  for (int q = 36; q < 108; ++q) {
    const int buf = q & 1;
    stage(q + 1, buf ^ 1);
    const unsigned short* bb = &s_b[buf][0];
#pragma unroll
    for (int ks = 0; ks < 2; ++ks) {
      const int g = ks * 2 + hl;
      short8 a;
      if (q < 100) {  // spline over h
        const int h = (q - 36) * 4 + g;
        a = spline_pack(bf2f(s_stash[lrow * SST + h]));
      } else {  // silu over h
        const int hb = (q - 100) * 32 + g * 8;
        a = silu8(*(const short8*)&s_stash[lrow * SST + hb]);
      }
      const unsigned short* fb = bb + (g * 128 + nh * 64 + ln31) * 8;
#pragma unroll
      for (int f = 0; f < 2; ++f) {
        const short8 bfr = *(const short8*)(fb + f * 32 * 8);
        acc2[f] =
            __builtin_amdgcn_mfma_f32_32x32x16_bf16(a, bfr, acc2[f], 0, 0, 0);
      }
    }
    __syncthreads();
  }

  // ==================== epilogue: LDS bounce -> coalesced residual ========
  float* ob = (float*)&s_stash[0];  // 2 groups x 128 c x 32 rows f32 = 32 KB
#pragma unroll
  for (int f = 0; f < 2; ++f)
#pragma unroll
    for (int r = 0; r < 16; ++r) {
      const int c = nh * 64 + f * 32 + ln31;
      const int row = 4 * hl + (r & 3) + 8 * (r >> 2);
      ob[gr * 4096 + c * 32 + (row ^ ((c & 7) << 2))] = acc2[f][r];
    }
  __syncthreads();
#pragma unroll
  for (int it = 0; it < 8; ++it) {
    const int slot = it * 256 + tid;
    const int gr2 = slot >> 10, rem = slot & 1023;
    const int c = rem >> 3, rg = rem & 7;
    const int p4 = (rg * 4) ^ ((c & 7) << 2);
    const float4 v = *(const float4*)&ob[gr2 * 4096 + c * 32 + p4];
    const size_t ga = ((size_t)b * Cn + c) * Tn + t0 + gr2 * 32 + rg * 4;
    const float4 u4 = *(const float4*)&U[ga];
    float4 o;
    o.x = u4.x + v.x;
    o.y = u4.y + v.y;
    o.z = u4.z + v.z;
    o.w = u4.w + v.w;
    *(float4*)&out[ga] = o;
  }
}

extern "C" void kernel_launch(void* const* d_in, const int* in_sizes, int n_in,
                              void* d_out, int out_size, void* d_ws,
                              size_t ws_size, hipStream_t stream) {
  const float* U = (const float*)d_in[0];
  const float* ln_w = (const float*)d_in[1];
  const float* ln_b = (const float*)d_in[2];
  const float* bw1 = (const float*)d_in[3];
  const float* sw1 = (const float*)d_in[4];
  const float* ss1 = (const float*)d_in[5];
  const float* bw2 = (const float*)d_in[6];
  const float* sw2 = (const float*)d_in[7];
  const float* ss2 = (const float*)d_in[8];
  float* out = (float*)d_out;

  char* ws = (char*)d_ws;
  float* stats = (float*)ws;                            // 4 KB
  unsigned short* lnwT = (unsigned short*)(ws + 4096);  // 128 KB
  unsigned short* lnbT = lnwT + Cn * Tn;                // 128 KB
  unsigned short* Wp = lnbT + Cn * Tn;                  // 1,179,648 B packed W

  kan_prep<<<640, 256, 0, stream>>>(U, ln_w, ln_b, bw1, sw1, ss1, bw2, sw2,
                                    ss2, Wp, lnwT, lnbT, stats);
  kan_fused<<<Bn * TB, 256, 0, stream>>>(U, lnwT, lnbT, Wp, stats, out);
}

// Round 11
// 144.577 us; speedup vs baseline: 1.7629x; 1.7446x over previous
//
#include <hip/hip_runtime.h>
#include <math.h>

namespace {

constexpr int Bn = 64, Cn = 128, Tn = 512, Hn = 256;
constexpr int MR = 128;        // t-rows per block
constexpr int TB = Tn / MR;    // 4 -> grid 256 (1 block/CU)
constexpr float LN_EPS = 1e-5f;

constexpr int L2BASE = 294912;  // short offset of L2 weight region (36*8192)
constexpr int SST = 258;        // stash row stride shorts (129 dw -> conflict-free u16 rows)
constexpr int ARS = 72;         // act row stride shorts (144B, 16B-aligned)
constexpr int NU = 72;          // staging units (36 L1 + 36 L2), 16 KB each

typedef __attribute__((ext_vector_type(8))) short short8;
typedef __attribute__((ext_vector_type(16))) float f32x16;

__device__ __forceinline__ unsigned short f2bf(float f) {
  unsigned int u = __builtin_bit_cast(unsigned int, f);
  u = (u + 0x7fffu + ((u >> 16) & 1u)) >> 16;
  return (unsigned short)u;
}
__device__ __forceinline__ float bf2f(unsigned short u) {
  unsigned int v = (unsigned int)u << 16;
  return __builtin_bit_cast(float, v);
}
__device__ __forceinline__ float siluf(float z) {
  return z * __builtin_amdgcn_rcpf(1.0f + __expf(-z));
}

// Closed-form uniform cubic B-spline on grid g[j]=0.4*(j-3)-1; 8 bases bf16.
__device__ __forceinline__ short8 spline_pack(float z) {
  const float p = z * 2.5f + 5.5f;
  const float fi = floorf(p);
  const int ib = (int)fi - 3;
  const float u = p - fi;
  const float u2 = u * u, u3 = u2 * u, tt = 1.0f - u;
  const float w0 = tt * tt * tt * (1.0f / 6.0f);
  const float w1 = (3.0f * u3 - 6.0f * u2 + 4.0f) * (1.0f / 6.0f);
  const float w2 = (-3.0f * u3 + 3.0f * u2 + 3.0f * u + 1.0f) * (1.0f / 6.0f);
  const float w3 = u3 * (1.0f / 6.0f);
  short8 r;
#pragma unroll
  for (int j = 0; j < 8; ++j) {
    const int d = j - ib;
    const float v =
        (d == 0) ? w0 : (d == 1) ? w1 : (d == 2) ? w2 : (d == 3) ? w3 : 0.0f;
    r[j] = (short)f2bf(v);
  }
  return r;
}

// 8 silus of 8 consecutive stash bf16 (read as 4 aligned dwords).
__device__ __forceinline__ short8 silu8_at(const unsigned short* p) {
  const unsigned int* q = (const unsigned int*)p;  // 4B-aligned (even offset)
  short8 a;
#pragma unroll
  for (int i = 0; i < 4; ++i) {
    const unsigned int v = q[i];
    a[2 * i] = (short)f2bf(siluf(bf2f((unsigned short)(v & 0xffffu))));
    a[2 * i + 1] = (short)f2bf(siluf(bf2f((unsigned short)(v >> 16))));
  }
  return a;
}

}  // namespace

// ---------------------------------------------------------------------------
// Prep (validated in round 10, unchanged): fragment-linear weight pack,
// LN partial sums, bf16 transpose of ln_w/ln_b to [c][t].
// ---------------------------------------------------------------------------
__global__ __launch_bounds__(256) void kan_prep(
    const float* __restrict__ U, const float* __restrict__ ln_w,
    const float* __restrict__ ln_b, const float* __restrict__ bw1,
    const float* __restrict__ sw1, const float* __restrict__ ss1,
    const float* __restrict__ bw2, const float* __restrict__ sw2,
    const float* __restrict__ ss2, unsigned short* __restrict__ Wp,
    unsigned short* __restrict__ lnwT, unsigned short* __restrict__ lnbT,
    float* __restrict__ stats) {
  __shared__ float red[2][4];
  const int blk = blockIdx.x;
  if (blk < 128) {  // ---- W1: idx = h*128 + c ----
    const int idx = blk * 256 + threadIdx.x;
    const int h = idx >> 7, c = idx & 127;
    const float sc = ss1[idx];
    const float* spw = sw1 + (size_t)idx * 8;
    short8 v;
#pragma unroll
    for (int j = 0; j < 8; ++j) v[j] = (short)f2bf(spw[j] * sc);
    *(short8*)(Wp + (size_t)(c >> 2) * 8192 + ((c & 3) * 256 + h) * 8) = v;
    Wp[(size_t)(32 + (c >> 5)) * 8192 + (((c >> 3) & 3) * 256 + h) * 8 +
       (c & 7)] = f2bf(bw1[idx]);
  } else if (blk < 256) {  // ---- W2: idx = c*256 + h ----
    const int idx = (blk - 128) * 256 + threadIdx.x;
    const int c = idx >> 8, h = idx & 255;
    const float sc = ss2[idx];
    const float* spw = sw2 + (size_t)idx * 8;
    short8 v;
#pragma unroll
    for (int j = 0; j < 8; ++j) v[j] = (short)f2bf(spw[j] * sc);
    *(short8*)(Wp + L2BASE + (size_t)(h >> 2) * 4096 + ((h & 3) * 128 + c) * 8) =
        v;
    Wp[L2BASE + (size_t)(64 + (h >> 5)) * 4096 + (((h >> 3) & 3) * 128 + c) * 8 +
       (h & 7)] = f2bf(bw2[idx]);
  } else if (blk < 512) {  // ---- LN stats partials ----
    const int sblk = blk - 256;
    const int b = sblk >> 2, q = sblk & 3;
    const float4* p =
        (const float4*)(U + (size_t)b * (Cn * Tn) + q * (Cn * Tn / 4));
    float s = 0.f, s2 = 0.f;
#pragma unroll 4
    for (int i = threadIdx.x; i < (Cn * Tn / 4) / 4; i += 256) {
      const float4 v4 = p[i];
      s += v4.x + v4.y + v4.z + v4.w;
      s2 += v4.x * v4.x + v4.y * v4.y + v4.z * v4.z + v4.w * v4.w;
    }
#pragma unroll
    for (int off = 32; off > 0; off >>= 1) {
      s += __shfl_down(s, off);
      s2 += __shfl_down(s2, off);
    }
    if ((threadIdx.x & 63) == 0) {
      red[0][threadIdx.x >> 6] = s;
      red[1][threadIdx.x >> 6] = s2;
    }
    __syncthreads();
    if (threadIdx.x == 0) {
      stats[b * 8 + q * 2 + 0] = red[0][0] + red[0][1] + red[0][2] + red[0][3];
      stats[b * 8 + q * 2 + 1] = red[1][0] + red[1][1] + red[1][2] + red[1][3];
    }
  } else {  // ---- ln_w/ln_b transpose to bf16 [c][t] ----
    const int bb = blk - 512;
    const float* src = (bb < 64) ? ln_w : ln_b;
    unsigned short* dst = (bb < 64) ? lnwT : lnbT;
    const int base = (bb & 63) * 1024;
#pragma unroll
    for (int e2 = 0; e2 < 4; ++e2) {
      const int i = base + (int)threadIdx.x + e2 * 256;
      dst[i] = f2bf(src[(i & 511) * Cn + (i >> 9)]);
    }
  }
}

// ---------------------------------------------------------------------------
// Fused kernel: 256 blocks x 1024 threads (16 waves, 4m x 4n wave grid).
// z pre-staged in LDS (no global loads in loop); act produced once per block
// into dbuf'd LDS (one 16B store per z); weights DMA'd 2-ahead into a
// 3-deep ring with counted vmcnt(1) (never drained); one barrier per unit.
// ---------------------------------------------------------------------------
__global__ __launch_bounds__(1024) void kan_fused(
    const float* __restrict__ U, const unsigned short* __restrict__ lnwT,
    const unsigned short* __restrict__ lnbT,
    const unsigned short* __restrict__ Wp, const float* __restrict__ stats,
    float* __restrict__ out) {
  __shared__ __align__(16) unsigned short s_stash[MR * SST];  // 66,048 B
  __shared__ __align__(16) unsigned short s_w[3][8192];       // 49,152 B
  __shared__ __align__(16) unsigned short s_act[2][MR * ARS]; // 36,864 B

  const int tid = threadIdx.x;
  const int b = blockIdx.x >> 2;
  const int t0 = (blockIdx.x & 3) * MR;

  const float* sp = stats + b * 8;
  const float ssum = sp[0] + sp[2] + sp[4] + sp[6];
  const float ssq = sp[1] + sp[3] + sp[5] + sp[7];
  const float inv_n = 1.0f / (float)(Cn * Tn);
  const float mean = ssum * inv_n;
  const float rstd = rsqrtf(ssq * inv_n - mean * mean + LN_EPS);

  const int w = tid >> 6, l = tid & 63;
  const int ln31 = l & 31, hl = l >> 5;
  const int wm = w & 3;   // m-group: rows wm*32..+31
  const int wn = w >> 2;  // n-group

  // ---- weight DMA: one 16B load per thread per 16-KB unit ----
  auto stage = [&](int u, int buf) {
    const char* src = (const char*)Wp + (size_t)u * 16384 + (size_t)tid * 16;
    char* dst = (char*)&s_w[buf][0] + (size_t)tid * 16;
    __builtin_amdgcn_global_load_lds(
        (const __attribute__((address_space(1))) unsigned int*)src,
        (__attribute__((address_space(3))) unsigned int*)dst, 16, 0, 0);
  };

  // ---- act production: one z (or 8 silus) -> one 16B store ----
  auto act_produce = [&](int u, unsigned short* abuf) {
    if (u < 32) {  // L1 spline: 4 c x 128 rows
      if (tid < 512) {
        const int row = tid & 127, cl = tid >> 7;
        const float z = bf2f(s_stash[row * SST + u * 4 + cl]);
        *(short8*)&abuf[row * ARS + cl * 8] = spline_pack(z);
      }
    } else if (u < 36) {  // L1 silu: 32 c x 128 rows
      if (tid < 512) {
        const int row = tid & 127, gl = tid >> 7;
        const int cb = (u - 32) * 32 + gl * 8;
        *(short8*)&abuf[row * ARS + gl * 8] =
            silu8_at(&s_stash[row * SST + cb]);
      }
    } else if (u < 68) {  // L2 spline: 8 h x 128 rows
      const int row = tid & 127, hloc = tid >> 7;
      const float z = bf2f(s_stash[row * SST + (u - 36) * 8 + hloc]);
      *(short8*)&abuf[row * ARS + hloc * 8] = spline_pack(z);
    } else {  // L2 silu: 64 h x 128 rows
      const int row = tid & 127, gl = tid >> 7;
      const int hb = (u - 68) * 64 + gl * 8;
      *(short8*)&abuf[row * ARS + gl * 8] = silu8_at(&s_stash[row * SST + hb]);
    }
  };

  f32x16 acc1[2] = {};
  f32x16 acc2 = {};

  // =========================== prologue ===========================
  stage(0, 0);
  stage(1, 1);
  {  // z1 pre-stage: LN of the whole 128x128 tile into stash (bf16)
    const int c = tid >> 3, tg = tid & 7;
#pragma unroll
    for (int i = 0; i < 4; ++i) {
      const int tl = tg * 16 + i * 4;
      const float4 u4 =
          *(const float4*)&U[((size_t)b * Cn + c) * Tn + t0 + tl];
      const unsigned short* lw = &lnwT[c * Tn + t0 + tl];
      const unsigned short* lb = &lnbT[c * Tn + t0 + tl];
      float zz[4] = {u4.x, u4.y, u4.z, u4.w};
#pragma unroll
      for (int k = 0; k < 4; ++k) {
        const float z = (zz[k] - mean) * rstd * bf2f(lw[k]) + bf2f(lb[k]);
        s_stash[(tl + k) * SST + c] = f2bf(z);
      }
    }
  }
  asm volatile("s_waitcnt lgkmcnt(0)" ::: "memory");
  __builtin_amdgcn_s_barrier();
  act_produce(0, &s_act[0][0]);
  asm volatile("s_waitcnt vmcnt(1) lgkmcnt(0)" ::: "memory");
  __builtin_amdgcn_s_barrier();

  // =========================== main loop ===========================
  for (int u = 0; u < NU; ++u) {
    if (u + 2 < NU) stage(u + 2, (u + 2) % 3);
    if (u != 35 && u + 1 < NU) act_produce(u + 1, &s_act[(u + 1) & 1][0]);

    const unsigned short* ab = &s_act[u & 1][0];
    const unsigned short* wb = &s_w[u % 3][0];
    __builtin_amdgcn_s_setprio(1);
    if (u < 36) {  // L1 unit: k=32, N=256 (wave n-tile 64 = 2 frags)
#pragma unroll
      for (int ks = 0; ks < 2; ++ks) {
        const short8 a = *(const short8*)&ab[(wm * 32 + ln31) * ARS + ks * 16 +
                                             hl * 8];
        const int g = 2 * ks + hl;
#pragma unroll
        for (int f = 0; f < 2; ++f) {
          const short8 bf =
              *(const short8*)&wb[(g * 256 + wn * 64 + f * 32 + ln31) * 8];
          acc1[f] =
              __builtin_amdgcn_mfma_f32_32x32x16_bf16(a, bf, acc1[f], 0, 0, 0);
        }
      }
    } else {  // L2 unit: k=64 (2 subchunks), N=128 (wave n-tile 32 = 1 frag)
#pragma unroll
      for (int s = 0; s < 2; ++s)
#pragma unroll
        for (int ks = 0; ks < 2; ++ks) {
          const short8 a = *(const short8*)&ab[(wm * 32 + ln31) * ARS + s * 32 +
                                               ks * 16 + hl * 8];
          const int g = 2 * ks + hl;
          const short8 bf =
              *(const short8*)&wb[s * 4096 + (g * 128 + wn * 32 + ln31) * 8];
          acc2 = __builtin_amdgcn_mfma_f32_32x32x16_bf16(a, bf, acc2, 0, 0, 0);
        }
    }
    __builtin_amdgcn_s_setprio(0);

    if (u + 2 < NU) {
      asm volatile("s_waitcnt vmcnt(1) lgkmcnt(0)" ::: "memory");
    } else if (u + 1 < NU) {
      asm volatile("s_waitcnt vmcnt(0) lgkmcnt(0)" ::: "memory");
    } else {
      asm volatile("s_waitcnt lgkmcnt(0)" ::: "memory");
    }
    __builtin_amdgcn_s_barrier();

    if (u == 35) {  // ---- layer boundary: h1 -> stash, act(36) catch-up ----
#pragma unroll
      for (int f = 0; f < 2; ++f)
#pragma unroll
        for (int r = 0; r < 16; ++r) {
          const int row = wm * 32 + 4 * hl + (r & 3) + 8 * (r >> 2);
          s_stash[row * SST + wn * 64 + f * 32 + ln31] = f2bf(acc1[f][r]);
        }
      asm volatile("s_waitcnt lgkmcnt(0)" ::: "memory");
      __builtin_amdgcn_s_barrier();
      act_produce(36, &s_act[0][0]);
      asm volatile("s_waitcnt lgkmcnt(0)" ::: "memory");
      __builtin_amdgcn_s_barrier();
    }
  }

  // ============== epilogue: LDS bounce -> coalesced residual ==============
  float* ob = (float*)&s_stash[0];  // 4 groups x 128 c x 32 rows f32 = 64 KB
#pragma unroll
  for (int r = 0; r < 16; ++r) {
    const int c = wn * 32 + ln31;
    const int rr = 4 * hl + (r & 3) + 8 * (r >> 2);
    ob[wm * 4096 + c * 32 + (rr ^ ((c & 7) << 2))] = acc2[r];
  }
  asm volatile("s_waitcnt lgkmcnt(0)" ::: "memory");
  __builtin_amdgcn_s_barrier();
#pragma unroll
  for (int it = 0; it < 4; ++it) {
    const int slot = it * 1024 + tid;
    const int gr2 = slot >> 10, rem = slot & 1023;
    const int c = rem >> 3, rg = rem & 7;
    const int p4 = (rg * 4) ^ ((c & 7) << 2);
    const float4 v = *(const float4*)&ob[gr2 * 4096 + c * 32 + p4];
    const size_t ga = ((size_t)b * Cn + c) * Tn + t0 + gr2 * 32 + rg * 4;
    const float4 u4 = *(const float4*)&U[ga];
    float4 o;
    o.x = u4.x + v.x;
    o.y = u4.y + v.y;
    o.z = u4.z + v.z;
    o.w = u4.w + v.w;
    *(float4*)&out[ga] = o;
  }
}

extern "C" void kernel_launch(void* const* d_in, const int* in_sizes, int n_in,
                              void* d_out, int out_size, void* d_ws,
                              size_t ws_size, hipStream_t stream) {
  const float* U = (const float*)d_in[0];
  const float* ln_w = (const float*)d_in[1];
  const float* ln_b = (const float*)d_in[2];
  const float* bw1 = (const float*)d_in[3];
  const float* sw1 = (const float*)d_in[4];
  const float* ss1 = (const float*)d_in[5];
  const float* bw2 = (const float*)d_in[6];
  const float* sw2 = (const float*)d_in[7];
  const float* ss2 = (const float*)d_in[8];
  float* out = (float*)d_out;

  char* ws = (char*)d_ws;
  float* stats = (float*)ws;                            // 4 KB
  unsigned short* lnwT = (unsigned short*)(ws + 4096);  // 128 KB
  unsigned short* lnbT = lnwT + Cn * Tn;                // 128 KB
  unsigned short* Wp = lnbT + Cn * Tn;                  // 1,179,648 B packed W

  kan_prep<<<640, 256, 0, stream>>>(U, ln_w, ln_b, bw1, sw1, ss1, bw2, sw2,
                                    ss2, Wp, lnwT, lnbT, stats);
  kan_fused<<<Bn * TB, 1024, 0, stream>>>(U, lnwT, lnbT, Wp, stats, out);
}